// Round 7
// baseline (814.850 us; speedup 1.0000x reference)
//
#include <hip/hip_runtime.h>
#include <cmath>

#define NA 20000
#define NS 4
#define NE 8
#define DD 1008
#define BM 128
#define MAXT 157      // ceil(20000/128)
#define MAXROWS 20608 // gather coverage, >= worst padded total

typedef unsigned short u16;
typedef unsigned int u32;
typedef unsigned long long u64;
typedef u16 u16x8 __attribute__((ext_vector_type(8)));
typedef u16 u16x4 __attribute__((ext_vector_type(4)));
typedef float f32x4 __attribute__((ext_vector_type(4)));
typedef short s16x8 __attribute__((ext_vector_type(8)));

__device__ __forceinline__ float bf2f(u16 h) {
  u32 u = ((u32)h) << 16;
  return __builtin_bit_cast(float, u);
}
__device__ __forceinline__ u16 f2bf(float f) {
  u32 b = __builtin_bit_cast(u32, f);
  u32 lsb = (b >> 16) & 1;
  return (u16)((b + 0x7fffu + lsb) >> 16);
}
// celu(x), alpha=0.1: x>0 ? x : 0.1*(e^{10x}-1). exp via v_exp_f32 (2^t).
__device__ __forceinline__ float celu_f(float x) {
#if __has_builtin(__builtin_amdgcn_exp2f)
  float e = __builtin_amdgcn_exp2f(x * 14.426950408889634f);
#else
  float e = exp2f(x * 14.426950408889634f);
#endif
  return x > 0.f ? x : 0.1f * (e - 1.f);
}
__device__ __forceinline__ float gf(const void* g, size_t i, bool isF32) {
  return isF32 ? ((const float*)g)[i] : bf2f(((const u16*)g)[i]);
}

// async global->LDS, 16B per lane; lds base wave-uniform, lane l -> base+l*16.
__device__ __forceinline__ void gll16(const void* g, const u16* lds) {
#if __has_builtin(__builtin_amdgcn_global_load_lds)
  __builtin_amdgcn_global_load_lds(
      (const __attribute__((address_space(1))) u32*)g,
      (__attribute__((address_space(3))) u32*)(u16*)lds, 16, 0, 0);
#else
  int l = threadIdx.x & 63;
  *(f32x4*)((u16*)lds + l * 8) = *(const f32x4*)g;
#endif
}

// ws ints: [0..3] counts, [4..7] cursors, [13..16] atom-base prefix,
// [17] f32 accum, [18] fp32-flag, [19] i64-flag, [20..23] padded segStart,
// [24] padded total, [25] count-ticket; order at int 1024.
__global__ void k_probe0(const void* __restrict__ aev, const void* __restrict__ species,
                         int* __restrict__ w) {
  __shared__ int sh[2];
  int tid = threadIdx.x;
  if (tid < 64) w[tid] = 0;
  if (tid == 0) { sh[0] = 0; sh[1] = 0; }
  __syncthreads();
  const u16* a = (const u16*)aev;
  int bad = 0;
  for (int i = 0; i < 16; ++i) {
    u16 h = a[tid * 16 + i];
    int ex = (h >> 7) & 0xFF;
    if (ex < 107 || ex > 147) ++bad;
  }
  atomicAdd(&sh[0], bad);
  const int* sp = (const int*)species;
  int odd = 0;
  for (int i = 0; i < 4; ++i)
    if (sp[(tid * 4 + i) * 2 + 1] != 0) ++odd;
  atomicAdd(&sh[1], odd);
  __syncthreads();
  if (tid == 0) {
    w[18] = (sh[0] > 400) ? 1 : 0;
    w[19] = (sh[1] == 0) ? 1 : 0;
  }
}

__device__ __forceinline__ int get_species(const void* sp, int i, bool i64) {
  int s = i64 ? ((const int*)sp)[2 * i] : ((const int*)sp)[i];
  return s < 0 ? 0 : (s > 3 ? 3 : s);
}

// count + fused scan (last-block ticket; non-blocking, no spin)
__global__ void k_count(const void* __restrict__ species, int* __restrict__ w) {
  int i = blockIdx.x * 256 + threadIdx.x;
  int lane = threadIdx.x & 63;
  int s = (i < NA) ? get_species(species, i, w[19] != 0) : -1;
  for (int sp = 0; sp < 4; ++sp) {
    u64 m = __ballot(s == sp);
    if (m != 0 && lane == (__ffsll((long long)m) - 1))
      atomicAdd(&w[sp], __popcll(m));
  }
  __syncthreads();
  if (threadIdx.x == 0) {
    __threadfence();
    if (atomicAdd(&w[25], 1) == (int)gridDim.x - 1) {
      int b = 0, pb = 0;
      for (int sp = 0; sp < 4; ++sp) {
        int c = atomicAdd(&w[sp], 0);  // coherent read
        w[13 + sp] = b; b += c;
        w[20 + sp] = pb; pb += ((c + 127) >> 7) << 7;
      }
      w[24] = pb;
    }
  }
}

// scatter (blocks 0..78) + small-tensor conversions (block 79)
__global__ void k_scatsml(const void* __restrict__ species, int* __restrict__ w,
                          int* __restrict__ order,
                          const void* b0, const void* b1, const void* b2, const void* b3,
                          const void* W3, u16* ob0, u16* ob1, u16* ob2, u16* ob3,
                          u16* oW3, u16* gap) {
  if (blockIdx.x == 79) {
    const bool isF32 = (w[18] != 0);
    int t = threadIdx.x;
    for (int i = t; i < 32 * 256; i += 256) ob0[i] = f2bf(gf(b0, i, isF32));
    for (int i = t; i < 32 * 192; i += 256) ob1[i] = f2bf(gf(b1, i, isF32));
    for (int i = t; i < 32 * 160; i += 256) ob2[i] = f2bf(gf(b2, i, isF32));
    for (int i = t; i < 32 * 160; i += 256) oW3[i] = f2bf(gf(W3, i, isF32));
    if (t < 32) ob3[t] = f2bf(gf(b3, t, isF32));
    u16x8 z = {0, 0, 0, 0, 0, 0, 0, 0};
    *(u16x8*)(gap + t * 8) = z;  // zero 4KB tail after aevb
    return;
  }
  int i = blockIdx.x * 256 + threadIdx.x;
  int lane = threadIdx.x & 63;
  int s = (i < NA) ? get_species(species, i, w[19] != 0) : -1;
  for (int sp = 0; sp < 4; ++sp) {
    u64 m = __ballot(s == sp);
    if (m == 0) continue;
    int leader = __ffsll((long long)m) - 1;
    int base = 0;
    if (lane == leader) base = atomicAdd(&w[4 + sp], __popcll(m));
    base = __shfl(base, leader);
    if (s == sp) {
      int rank = __popcll(m & ((lane == 63) ? 0x7fffffffffffffffULL : ((1ULL << lane) - 1)));
      order[w[13 + sp] + base + rank] = i;
    }
  }
}

// gather aev into sorted, per-species 128-padded bf16 rows; pad rows zeroed.
__global__ void k_gather(const void* __restrict__ aev, const int* __restrict__ w,
                         const int* __restrict__ order, u16* __restrict__ aevb) {
  const bool isF32 = (w[18] != 0);
  const int t = threadIdx.x;
  const int r = blockIdx.x * 4 + (t >> 7);
  const int j = t & 127;
  if (j >= 126) return;
  const int s = (r >= w[21]) + (r >= w[22]) + (r >= w[23]);
  const int local = r - w[20 + s];
  u16x8 v = {0, 0, 0, 0, 0, 0, 0, 0};
  if (local < w[s]) {
    const int src = order[w[13 + s] + local];
    if (isF32) {
      const float* p = (const float*)aev + (size_t)src * DD + j * 8;
      const f32x4 f0 = *(const f32x4*)p;
      const f32x4 f1 = *(const f32x4*)(p + 4);
#pragma unroll
      for (int i = 0; i < 4; ++i) { v[i] = f2bf(f0[i]); v[4 + i] = f2bf(f1[i]); }
    } else {
      v = *(const u16x8*)((const u16*)aev + (size_t)src * DD + j * 8);
    }
  }
  *(u16x8*)(aevb + (size_t)r * DD + j * 8) = v;
}

// one 64x64 transpose tile: W [se][K][N] -> bf16 [se][N][Kpad], zero-padded K
__device__ void tr_tile(const void* __restrict__ W, u16* __restrict__ out,
                        int K, int N, int Kpad, bool isF32, int se,
                        int k0, int n0, int t, u16 (*tile)[68]) {
  const size_t inBase = (size_t)se * K * N;
#pragma unroll
  for (int c = 0; c < 4; ++c) {
    int kk = (t >> 4) + c * 16, nn = (t & 15) * 4;
    int k = k0 + kk, n = n0 + nn;
    u16x4 v = {0, 0, 0, 0};
    if (k < K && n < N) {
      if (isF32) {
        f32x4 f = *(const f32x4*)((const float*)W + inBase + (size_t)k * N + n);
        v[0] = f2bf(f[0]); v[1] = f2bf(f[1]); v[2] = f2bf(f[2]); v[3] = f2bf(f[3]);
      } else {
        v = *(const u16x4*)((const u16*)W + inBase + (size_t)k * N + n);
      }
    }
    *(u16x4*)(&tile[kk][nn]) = v;
  }
  __syncthreads();
  int nloc = t >> 2, ks = (t & 3) * 16;
  if (n0 + nloc < N) {
    u16x8 o0, o1;
#pragma unroll
    for (int i = 0; i < 8; ++i) { o0[i] = tile[ks + i][nloc]; o1[i] = tile[ks + 8 + i][nloc]; }
    size_t ob = (size_t)se * N * Kpad + (size_t)(n0 + nloc) * Kpad + k0 + ks;
    *(u16x8*)(out + ob) = o0;
    *(u16x8*)(out + ob + 8) = o1;
  }
}

// all three weight transposes in one launch; grid (32,16,4)
__global__ void k_tr3(const void* __restrict__ W0, const void* __restrict__ W1,
                      const void* __restrict__ W2, u16* __restrict__ o0,
                      u16* __restrict__ o1, u16* __restrict__ o2,
                      const int* __restrict__ w) {
  __shared__ u16 tile[64][68];
  const bool isF32 = (w[18] != 0);
  const int se = blockIdx.x, by = blockIdx.y, bz = blockIdx.z, t = threadIdx.x;
  tr_tile(W0, o0, 1008, 256, 1024, isF32, se, by * 64, bz * 64, t, tile);
  if (by < 4 && bz < 3) {
    __syncthreads();
    tr_tile(W1, o1, 256, 192, 256, isF32, se, by * 64, bz * 64, t, tile);
  }
  if (by < 3 && bz < 3) {
    __syncthreads();
    tr_tile(W2, o2, 192, 160, 192, isF32, se, by * 64, bz * 64, t, tile);
  }
}

// ================= fused MFMA kernel =================
// 1024 threads = 16 waves; block = 128 atoms (one species) x one e.
// Occupancy lever (R6 post-mortem): LDS pegs 2 blocks/CU; at 512 thr that was
// 4 waves/SIMD with every pipe <35% busy (latency-starved). Same 2 blocks at
// 1024 thr = 32 waves/CU = 8 waves/SIMD. launch_bounds(1024,8) caps VGPR at
// 64 (acc[2][4]=32 + frags 24 fits).
// Grid (8, 4*MAXT): x = group = s*2+(e>>2) -> flat%8 pins group to one XCD.
// L0: BM=128 x N=256 x K=1024(pad), BK=32, A+B staged via global_load_lds,
// double-buffered, depth-1, drain barrier per phase (R2-proven; R6 proved
// counted-vmcnt is equivalent here). Wave grid 4m x 4n, wave tile 32x64,
// 8 MFMA/phase.
// Staging swizzle (both-sides, rule 21): granule g of row r at slot
// g ^ ((r>>1)&3); fragment reads use the same XOR -> conflict-free b128.
// LDS union: {A-dbuf 8KB | B-dbuf 32KB} -> H0 64KB -> H1 48KB -> H2 40KB.
// H tensors XOR-swizzled: u16 idx ^= (row&7)<<3.
// mfma_f32_16x16x32_bf16: A[m=lane&15][k=quad*8+j]; B[k][n=lane&15];
// C/D col=lane&15, row=quad*4+reg (m89-verified).
__global__ __launch_bounds__(1024, 8) void k_main(
    const u16* __restrict__ aevb, const u16* __restrict__ wt0,
    const u16* __restrict__ wt1, const u16* __restrict__ wt2,
    const u16* __restrict__ w3b, const u16* __restrict__ b0b,
    const u16* __restrict__ b1b, const u16* __restrict__ b2b,
    const u16* __restrict__ b3b, const int* __restrict__ w,
    float* __restrict__ accum) {
  __shared__ __align__(16) u16 L[32768];

  const int tid = threadIdx.x;
  const int g = blockIdx.x;
  const int s = g >> 1;
  const int e = (g & 1) * 4 + (blockIdx.y & 3);
  const int tile = blockIdx.y >> 2;
  const int cnt = w[s];
  if (tile * BM >= cnt) return;
  const int mRow = w[20 + s] + tile * BM;
  const int mCount = min(BM, cnt - tile * BM);
  const int se = s * NE + e;

  const int lane = tid & 63;
  const int wv = tid >> 6;       // 0..15
  const int lcol = lane & 15;
  const int quad = lane >> 4;

  // ---------------- layer 0: aevb[128x1008] @ wt0t[se][256][1024] ----------------
  {
    const u16* wt0se = wt0 + (size_t)se * 256 * 1024;
    const int wm = wv >> 2, wn = wv & 3;   // 4x4 wave grid, tile 32x64

    // A staging (tid<512): slot=tid, row=tid>>2 (0..127), pos=tid&3,
    // src granule = pos ^ ((row>>1)&3). B staging (all 1024): slot=tid,
    // row=tid>>2 (0..255), same swizzle.
    const int rowA = tid >> 2;
    const int gAx = (tid & 3) ^ ((rowA >> 1) & 3);
    const u16* gA = aevb + (size_t)(mRow + (rowA & 127)) * 1008 + gAx * 8;
    const int rowB = tid >> 2;
    const int gBx = (tid & 3) ^ ((rowB >> 1) & 3);
    const u16* gB = wt0se + (size_t)rowB * 1024 + gBx * 8;
    const int aSt = wv * 512;   // wave-uniform u16 offset (waves 0..7 only)
    const int bSt = wv * 512;   // wave-uniform u16 offset within B buf

    // fragment read swizzle (lane-constant XOR term)
    const int gsw = (quad ^ ((lcol >> 1) & 3)) * 8;
    const int aRow0 = (wm * 32 + lcol) * 32 + gsw;
    const int bRow0 = (wn * 64 + lcol) * 32 + gsw;

    f32x4 acc[2][4];
#pragma unroll
    for (int i = 0; i < 2; ++i)
#pragma unroll
      for (int j = 0; j < 4; ++j) acc[i][j] = (f32x4){0.f, 0.f, 0.f, 0.f};

    // prologue: stage phase 0 into buffer 0
    if (tid < 512) gll16(gA, &L[aSt]);
    gll16(gB, &L[8192 + bSt]);
    __syncthreads();

    for (int p = 0; p < 32; ++p) {
      const int d = p & 1;
      if (p < 31) {
        const int dn = d ^ 1;
        if (tid < 512) gll16(gA + (p + 1) * 32, &L[dn * 4096 + aSt]);
        gll16(gB + (p + 1) * 32, &L[8192 + dn * 8192 + bSt]);
      }
      const u16* Ad = &L[d * 4096];
      const u16* Bd = &L[8192 + d * 8192];
      s16x8 aF[2], bF[4];
#pragma unroll
      for (int mt = 0; mt < 2; ++mt)
        aF[mt] = __builtin_bit_cast(s16x8, *(const u16x8*)(Ad + aRow0 + mt * 512));
#pragma unroll
      for (int nt = 0; nt < 4; ++nt)
        bF[nt] = __builtin_bit_cast(s16x8, *(const u16x8*)(Bd + bRow0 + nt * 512));
      __builtin_amdgcn_s_setprio(1);
#pragma unroll
      for (int nt = 0; nt < 4; ++nt)
#pragma unroll
        for (int mt = 0; mt < 2; ++mt)
          acc[mt][nt] = __builtin_amdgcn_mfma_f32_16x16x32_bf16(aF[mt], bF[nt], acc[mt][nt], 0, 0, 0);
      __builtin_amdgcn_s_setprio(0);
      __syncthreads();
    }

    // epilogue -> H0 [128][256] swizzled (staging dead after final barrier)
#pragma unroll
    for (int nt = 0; nt < 4; ++nt) {
      const int col = wn * 64 + nt * 16 + lcol;
      const float bb = bf2f(b0b[se * 256 + col]);
#pragma unroll
      for (int mt = 0; mt < 2; ++mt) {
#pragma unroll
        for (int r = 0; r < 4; ++r) {
          const int rr = wm * 32 + mt * 16 + quad * 4 + r;
          L[(rr * 256 + col) ^ ((rr & 7) << 3)] = f2bf(celu_f(acc[mt][nt][r] + bb));
        }
      }
    }
  }
  __syncthreads();

  // ---------------- layer 1: H0[128x256] @ wt1t[192][256] ----------------
  {
    const int wm = wv >> 2, wn = wv & 3;   // 4x4, wave tile 32x48
    const u16* w1se = wt1 + (size_t)se * 192 * 256;
    const u16* bp[3];
#pragma unroll
    for (int nt = 0; nt < 3; ++nt)
      bp[nt] = w1se + (size_t)(wn * 48 + nt * 16 + lcol) * 256 + quad * 8;
    f32x4 acc[2][3];
#pragma unroll
    for (int i = 0; i < 2; ++i)
#pragma unroll
      for (int j = 0; j < 3; ++j) acc[i][j] = (f32x4){0.f, 0.f, 0.f, 0.f};
    int aBase[2], aSwz[2];
#pragma unroll
    for (int mt = 0; mt < 2; ++mt) {
      const int row = wm * 32 + mt * 16 + lcol;
      aBase[mt] = row * 256 + quad * 8;
      aSwz[mt] = (row & 7) << 3;
    }
    u16x8 cB[3], nB[3];
#pragma unroll
    for (int nt = 0; nt < 3; ++nt) cB[nt] = *(const u16x8*)bp[nt];
    for (int kc = 0; kc < 8; ++kc) {
      if (kc < 7) {
#pragma unroll
        for (int nt = 0; nt < 3; ++nt) nB[nt] = *(const u16x8*)(bp[nt] + (kc + 1) * 32);
      }
      s16x8 aF[2];
#pragma unroll
      for (int mt = 0; mt < 2; ++mt)
        aF[mt] = __builtin_bit_cast(s16x8, *(const u16x8*)&L[(aBase[mt] + kc * 32) ^ aSwz[mt]]);
#pragma unroll
      for (int nt = 0; nt < 3; ++nt) {
        const s16x8 bF = __builtin_bit_cast(s16x8, cB[nt]);
#pragma unroll
        for (int mt = 0; mt < 2; ++mt)
          acc[mt][nt] = __builtin_amdgcn_mfma_f32_16x16x32_bf16(aF[mt], bF, acc[mt][nt], 0, 0, 0);
      }
      if (kc < 7) {
#pragma unroll
        for (int nt = 0; nt < 3; ++nt) cB[nt] = nB[nt];
      }
    }
    __syncthreads();  // all H0 reads done
#pragma unroll
    for (int nt = 0; nt < 3; ++nt) {
      const int col = wn * 48 + nt * 16 + lcol;
      const float bb = bf2f(b1b[se * 192 + col]);
#pragma unroll
      for (int mt = 0; mt < 2; ++mt) {
#pragma unroll
        for (int r = 0; r < 4; ++r) {
          const int rr = wm * 32 + mt * 16 + quad * 4 + r;
          L[(rr * 192 + col) ^ ((rr & 7) << 3)] = f2bf(celu_f(acc[mt][nt][r] + bb));
        }
      }
    }
  }
  __syncthreads();

  // ---------------- layer 2: H1[128x192] @ wt2t[160][192] ----------------
  {
    const int wm = wv >> 2, wn = wv & 3;   // 4x4; n-tiles 10 split 2/2/3/3
    const int nN2 = (wn < 2) ? 2 : 3;
    const int t2 = (wn < 2) ? 2 * wn : 3 * wn - 2;
    const u16* w2se = wt2 + (size_t)se * 160 * 192;
    const u16* bp[3];
    for (int nt = 0; nt < nN2; ++nt)
      bp[nt] = w2se + (size_t)((t2 + nt) * 16 + lcol) * 192 + quad * 8;
    f32x4 acc[2][3];
#pragma unroll
    for (int i = 0; i < 2; ++i)
#pragma unroll
      for (int j = 0; j < 3; ++j) acc[i][j] = (f32x4){0.f, 0.f, 0.f, 0.f};
    int aBase[2], aSwz[2];
#pragma unroll
    for (int mt = 0; mt < 2; ++mt) {
      const int row = wm * 32 + mt * 16 + lcol;
      aBase[mt] = row * 192 + quad * 8;
      aSwz[mt] = (row & 7) << 3;
    }
    u16x8 cB[3], nB[3];
    for (int nt = 0; nt < nN2; ++nt) cB[nt] = *(const u16x8*)bp[nt];
    for (int kc = 0; kc < 6; ++kc) {
      if (kc < 5) {
        for (int nt = 0; nt < nN2; ++nt) nB[nt] = *(const u16x8*)(bp[nt] + (kc + 1) * 32);
      }
      s16x8 aF[2];
#pragma unroll
      for (int mt = 0; mt < 2; ++mt)
        aF[mt] = __builtin_bit_cast(s16x8, *(const u16x8*)&L[(aBase[mt] + kc * 32) ^ aSwz[mt]]);
      for (int nt = 0; nt < nN2; ++nt) {
        const s16x8 bF = __builtin_bit_cast(s16x8, cB[nt]);
#pragma unroll
        for (int mt = 0; mt < 2; ++mt)
          acc[mt][nt] = __builtin_amdgcn_mfma_f32_16x16x32_bf16(aF[mt], bF, acc[mt][nt], 0, 0, 0);
      }
      if (kc < 5) {
        for (int nt = 0; nt < nN2; ++nt) cB[nt] = nB[nt];
      }
    }
    __syncthreads();  // all H1 reads done
    for (int nt = 0; nt < nN2; ++nt) {
      const int col = (t2 + nt) * 16 + lcol;
      const float bb = bf2f(b2b[se * 160 + col]);
#pragma unroll
      for (int mt = 0; mt < 2; ++mt) {
#pragma unroll
        for (int r = 0; r < 4; ++r) {
          const int rr = wm * 32 + mt * 16 + quad * 4 + r;
          L[(rr * 160 + col) ^ ((rr & 7) << 3)] = f2bf(celu_f(acc[mt][nt][r] + bb));
        }
      }
    }
  }
  __syncthreads();

  // ---------------- layer 3: dot(H2[128x160], W3) + b3, reduce ----------------
  {
    const int row = tid >> 3;   // 0..127
    const int pp = tid & 7;     // 8 parts per row
    const u16* w3p = w3b + se * 160;
    float dotv = 0.f;
    // granules pp, pp+8 (all), 16+pp (pp<4): 20 granules of 8 cols
#pragma unroll
    for (int j = 0; j < 2; ++j) {
      const int ci = (pp + 8 * j) * 8;
      const u16x8 hv = *(const u16x8*)&L[(row * 160 + ci) ^ ((row & 7) << 3)];
      const u16x8 wv8 = *(const u16x8*)(w3p + ci);
#pragma unroll
      for (int t2 = 0; t2 < 8; ++t2)
        dotv = fmaf(bf2f(hv[t2]), bf2f(wv8[t2]), dotv);
    }
    if (pp < 4) {
      const int ci = (16 + pp) * 8;
      const u16x8 hv = *(const u16x8*)&L[(row * 160 + ci) ^ ((row & 7) << 3)];
      const u16x8 wv8 = *(const u16x8*)(w3p + ci);
#pragma unroll
      for (int t2 = 0; t2 < 8; ++t2)
        dotv = fmaf(bf2f(hv[t2]), bf2f(wv8[t2]), dotv);
    }
    dotv += __shfl_xor(dotv, 1);
    dotv += __shfl_xor(dotv, 2);
    dotv += __shfl_xor(dotv, 4);
    float v = (pp == 0 && row < mCount) ? (dotv + bf2f(b3b[se])) : 0.f;
    v += __shfl_xor(v, 8);
    v += __shfl_xor(v, 16);
    v += __shfl_xor(v, 32);
    float* redf = (float*)&L[20608];  // beyond H2 swizzled extent (<20536)
    if (lane == 0) redf[wv] = v;
    __syncthreads();
    if (tid == 0) {
      float tot = 0.f;
#pragma unroll
      for (int i = 0; i < 16; ++i) tot += redf[i];
      atomicAdd(accum, tot * 0.125f);
    }
  }
}

__global__ void k_final(const float* __restrict__ accum, u32* __restrict__ out) {
  u32 h = (u32)f2bf(accum[0]);
  out[0] = (h << 16) | h;
}

extern "C" void kernel_launch(void* const* d_in, const int* in_sizes, int n_in,
                              void* d_out, int out_size, void* d_ws, size_t ws_size,
                              hipStream_t stream) {
  const void* aev = d_in[0];
  const void* species = d_in[1];
  const void* W0 = d_in[2];
  const void* b0 = d_in[3];
  const void* W1 = d_in[4];
  const void* b1 = d_in[5];
  const void* W2 = d_in[6];
  const void* b2 = d_in[7];
  const void* W3 = d_in[8];
  const void* b3 = d_in[9];

  int* wsI = (int*)d_ws;
  float* accum = (float*)((char*)d_ws + 17 * 4);
  int* order = wsI + 1024;  // byte offset 4096, 80000B
  char* wsB = (char*)d_ws;

  const size_t oB0 = 131072;
  const size_t oB1 = 147456;
  const size_t oB2 = 159744;
  const size_t oB3 = 169984;
  const size_t oW3 = 170048;
  const size_t oAevb = 262144;         // 20608*2016 = 41545728 -> 41807872
  const size_t oGap = 41807872;        // 4KB zeroed guard
  const size_t oWt0 = 41811968;        // 16777216 -> 58589184
  const size_t oWt1 = 58589184;        // 3145728 -> 61734912
  const size_t oWt2 = 61734912;        // 1966080 -> 63700992

  u16* aevb = (u16*)(wsB + oAevb);
  u16* wt0 = (u16*)(wsB + oWt0);
  u16* wt1 = (u16*)(wsB + oWt1);
  u16* wt2 = (u16*)(wsB + oWt2);
  u16* w3b = (u16*)(wsB + oW3);
  u16* b0b = (u16*)(wsB + oB0);
  u16* b1b = (u16*)(wsB + oB1);
  u16* b2b = (u16*)(wsB + oB2);
  u16* b3b = (u16*)(wsB + oB3);

  hipLaunchKernelGGL(k_probe0, dim3(1), dim3(256), 0, stream, aev, species, wsI);
  hipLaunchKernelGGL(k_count, dim3((NA + 255) / 256), dim3(256), 0, stream, species, wsI);
  hipLaunchKernelGGL(k_scatsml, dim3(80), dim3(256), 0, stream, species, wsI, order,
                     b0, b1, b2, b3, W3, b0b, b1b, b2b, b3b, w3b, (u16*)(wsB + oGap));
  hipLaunchKernelGGL(k_gather, dim3(MAXROWS / 4), dim3(512), 0, stream, aev, wsI, order, aevb);
  hipLaunchKernelGGL(k_tr3, dim3(32, 16, 4), dim3(256), 0, stream, W0, W1, W2,
                     wt0, wt1, wt2, wsI);
  hipLaunchKernelGGL(k_main, dim3(8, 4 * MAXT), dim3(1024), 0, stream,
                     aevb, wt0, wt1, wt2, w3b, b0b, b1b, b2b, b3b, wsI, accum);
  hipLaunchKernelGGL(k_final, dim3(1), dim3(1), 0, stream, accum, (u32*)d_out);
}

// Round 9
// 745.463 us; speedup vs baseline: 1.0931x; 1.0931x over previous
//
#include <hip/hip_runtime.h>
#include <cmath>

#define NA 20000
#define NS 4
#define NE 8
#define DD 1008
#define BM 64
#define MAXT 313      // ceil(20000/64)
#define MAXROWS 20608 // gather coverage, >= worst padded total

typedef unsigned short u16;
typedef unsigned int u32;
typedef unsigned long long u64;
typedef u16 u16x8 __attribute__((ext_vector_type(8)));
typedef u16 u16x4 __attribute__((ext_vector_type(4)));
typedef float f32x4 __attribute__((ext_vector_type(4)));
typedef short s16x8 __attribute__((ext_vector_type(8)));

__device__ __forceinline__ float bf2f(u16 h) {
  u32 u = ((u32)h) << 16;
  return __builtin_bit_cast(float, u);
}
__device__ __forceinline__ u16 f2bf(float f) {
  u32 b = __builtin_bit_cast(u32, f);
  u32 lsb = (b >> 16) & 1;
  return (u16)((b + 0x7fffu + lsb) >> 16);
}
// celu(x), alpha=0.1: x>0 ? x : 0.1*(e^{10x}-1). exp via v_exp_f32 (2^t).
__device__ __forceinline__ float celu_f(float x) {
#if __has_builtin(__builtin_amdgcn_exp2f)
  float e = __builtin_amdgcn_exp2f(x * 14.426950408889634f);
#else
  float e = exp2f(x * 14.426950408889634f);
#endif
  return x > 0.f ? x : 0.1f * (e - 1.f);
}
__device__ __forceinline__ float gf(const void* g, size_t i, bool isF32) {
  return isF32 ? ((const float*)g)[i] : bf2f(((const u16*)g)[i]);
}

// async global->LDS, 16B per lane; lds base wave-uniform, lane l -> base+l*16.
__device__ __forceinline__ void gll16(const void* g, const u16* lds) {
#if __has_builtin(__builtin_amdgcn_global_load_lds)
  __builtin_amdgcn_global_load_lds(
      (const __attribute__((address_space(1))) u32*)g,
      (__attribute__((address_space(3))) u32*)(u16*)lds, 16, 0, 0);
#else
  int l = threadIdx.x & 63;
  *(f32x4*)((u16*)lds + l * 8) = *(const f32x4*)g;
#endif
}

// ws ints: [0..3] counts, [4..7] cursors, [13..16] atom-base prefix,
// [17] f32 accum, [18] fp32-flag, [19] i64-flag, [20..23] padded segStart,
// [24] padded total, [25] count-ticket; order at int 1024.
__global__ void k_probe0(const void* __restrict__ aev, const void* __restrict__ species,
                         int* __restrict__ w) {
  __shared__ int sh[2];
  int tid = threadIdx.x;
  if (tid < 64) w[tid] = 0;
  if (tid == 0) { sh[0] = 0; sh[1] = 0; }
  __syncthreads();
  const u16* a = (const u16*)aev;
  int bad = 0;
  for (int i = 0; i < 16; ++i) {
    u16 h = a[tid * 16 + i];
    int ex = (h >> 7) & 0xFF;
    if (ex < 107 || ex > 147) ++bad;
  }
  atomicAdd(&sh[0], bad);
  const int* sp = (const int*)species;
  int odd = 0;
  for (int i = 0; i < 4; ++i)
    if (sp[(tid * 4 + i) * 2 + 1] != 0) ++odd;
  atomicAdd(&sh[1], odd);
  __syncthreads();
  if (tid == 0) {
    w[18] = (sh[0] > 400) ? 1 : 0;
    w[19] = (sh[1] == 0) ? 1 : 0;
  }
}

__device__ __forceinline__ int get_species(const void* sp, int i, bool i64) {
  int s = i64 ? ((const int*)sp)[2 * i] : ((const int*)sp)[i];
  return s < 0 ? 0 : (s > 3 ? 3 : s);
}

// count + fused scan (last-block ticket; non-blocking, no spin)
__global__ void k_count(const void* __restrict__ species, int* __restrict__ w) {
  int i = blockIdx.x * 256 + threadIdx.x;
  int lane = threadIdx.x & 63;
  int s = (i < NA) ? get_species(species, i, w[19] != 0) : -1;
  for (int sp = 0; sp < 4; ++sp) {
    u64 m = __ballot(s == sp);
    if (m != 0 && lane == (__ffsll((long long)m) - 1))
      atomicAdd(&w[sp], __popcll(m));
  }
  __syncthreads();
  if (threadIdx.x == 0) {
    __threadfence();
    if (atomicAdd(&w[25], 1) == (int)gridDim.x - 1) {
      int b = 0, pb = 0;
      for (int sp = 0; sp < 4; ++sp) {
        int c = atomicAdd(&w[sp], 0);  // coherent read
        w[13 + sp] = b; b += c;
        w[20 + sp] = pb; pb += ((c + 63) >> 6) << 6;  // 64-row padding (BM=64)
      }
      w[24] = pb;
    }
  }
}

// scatter (blocks 0..78) + small-tensor conversions (block 79)
__global__ void k_scatsml(const void* __restrict__ species, int* __restrict__ w,
                          int* __restrict__ order,
                          const void* b0, const void* b1, const void* b2, const void* b3,
                          const void* W3, u16* ob0, u16* ob1, u16* ob2, u16* ob3,
                          u16* oW3, u16* gap) {
  if (blockIdx.x == 79) {
    const bool isF32 = (w[18] != 0);
    int t = threadIdx.x;
    for (int i = t; i < 32 * 256; i += 256) ob0[i] = f2bf(gf(b0, i, isF32));
    for (int i = t; i < 32 * 192; i += 256) ob1[i] = f2bf(gf(b1, i, isF32));
    for (int i = t; i < 32 * 160; i += 256) ob2[i] = f2bf(gf(b2, i, isF32));
    for (int i = t; i < 32 * 160; i += 256) oW3[i] = f2bf(gf(W3, i, isF32));
    if (t < 32) ob3[t] = f2bf(gf(b3, t, isF32));
    u16x8 z = {0, 0, 0, 0, 0, 0, 0, 0};
    *(u16x8*)(gap + t * 8) = z;  // zero 4KB tail after aevb
    return;
  }
  int i = blockIdx.x * 256 + threadIdx.x;
  int lane = threadIdx.x & 63;
  int s = (i < NA) ? get_species(species, i, w[19] != 0) : -1;
  for (int sp = 0; sp < 4; ++sp) {
    u64 m = __ballot(s == sp);
    if (m == 0) continue;
    int leader = __ffsll((long long)m) - 1;
    int base = 0;
    if (lane == leader) base = atomicAdd(&w[4 + sp], __popcll(m));
    base = __shfl(base, leader);
    if (s == sp) {
      int rank = __popcll(m & ((lane == 63) ? 0x7fffffffffffffffULL : ((1ULL << lane) - 1)));
      order[w[13 + sp] + base + rank] = i;
    }
  }
}

// gather aev into sorted, per-species 64-padded bf16 rows; pad rows zeroed.
__global__ void k_gather(const void* __restrict__ aev, const int* __restrict__ w,
                         const int* __restrict__ order, u16* __restrict__ aevb) {
  const bool isF32 = (w[18] != 0);
  const int t = threadIdx.x;
  const int r = blockIdx.x * 4 + (t >> 7);
  const int j = t & 127;
  if (j >= 126) return;
  const int s = (r >= w[21]) + (r >= w[22]) + (r >= w[23]);
  const int local = r - w[20 + s];
  u16x8 v = {0, 0, 0, 0, 0, 0, 0, 0};
  if (local < w[s]) {
    const int src = order[w[13 + s] + local];
    if (isF32) {
      const float* p = (const float*)aev + (size_t)src * DD + j * 8;
      const f32x4 f0 = *(const f32x4*)p;
      const f32x4 f1 = *(const f32x4*)(p + 4);
#pragma unroll
      for (int i = 0; i < 4; ++i) { v[i] = f2bf(f0[i]); v[4 + i] = f2bf(f1[i]); }
    } else {
      v = *(const u16x8*)((const u16*)aev + (size_t)src * DD + j * 8);
    }
  }
  *(u16x8*)(aevb + (size_t)r * DD + j * 8) = v;
}

// one 64x64 transpose tile: W [se][K][N] -> bf16 [se][N][Kpad], zero-padded K
__device__ void tr_tile(const void* __restrict__ W, u16* __restrict__ out,
                        int K, int N, int Kpad, bool isF32, int se,
                        int k0, int n0, int t, u16 (*tile)[68]) {
  const size_t inBase = (size_t)se * K * N;
#pragma unroll
  for (int c = 0; c < 4; ++c) {
    int kk = (t >> 4) + c * 16, nn = (t & 15) * 4;
    int k = k0 + kk, n = n0 + nn;
    u16x4 v = {0, 0, 0, 0};
    if (k < K && n < N) {
      if (isF32) {
        f32x4 f = *(const f32x4*)((const float*)W + inBase + (size_t)k * N + n);
        v[0] = f2bf(f[0]); v[1] = f2bf(f[1]); v[2] = f2bf(f[2]); v[3] = f2bf(f[3]);
      } else {
        v = *(const u16x4*)((const u16*)W + inBase + (size_t)k * N + n);
      }
    }
    *(u16x4*)(&tile[kk][nn]) = v;
  }
  __syncthreads();
  int nloc = t >> 2, ks = (t & 3) * 16;
  if (n0 + nloc < N) {
    u16x8 o0, o1;
#pragma unroll
    for (int i = 0; i < 8; ++i) { o0[i] = tile[ks + i][nloc]; o1[i] = tile[ks + 8 + i][nloc]; }
    size_t ob = (size_t)se * N * Kpad + (size_t)(n0 + nloc) * Kpad + k0 + ks;
    *(u16x8*)(out + ob) = o0;
    *(u16x8*)(out + ob + 8) = o1;
  }
}

// all three weight transposes in one launch; grid (32,16,4)
__global__ void k_tr3(const void* __restrict__ W0, const void* __restrict__ W1,
                      const void* __restrict__ W2, u16* __restrict__ o0,
                      u16* __restrict__ o1, u16* __restrict__ o2,
                      const int* __restrict__ w) {
  __shared__ u16 tile[64][68];
  const bool isF32 = (w[18] != 0);
  const int se = blockIdx.x, by = blockIdx.y, bz = blockIdx.z, t = threadIdx.x;
  tr_tile(W0, o0, 1008, 256, 1024, isF32, se, by * 64, bz * 64, t, tile);
  if (by < 4 && bz < 3) {
    __syncthreads();
    tr_tile(W1, o1, 256, 192, 256, isF32, se, by * 64, bz * 64, t, tile);
  }
  if (by < 3 && bz < 3) {
    __syncthreads();
    tr_tile(W2, o2, 192, 160, 192, isF32, se, by * 64, bz * 64, t, tile);
  }
}

// ================= fused MFMA kernel =================
// 512 threads = 8 waves; block = 64 atoms (one species) x one e.
// Occupancy fix (R7 post-mortem: VGPR cap 64 -> spills): BM=64 shrinks the
// LDS window to 40KB (A-dbuf 8K + B-dbuf 32K; H0 32K overlays) -> 3 blocks/CU
// = 24 waves/CU = 6 waves/SIMD. launch_bounds(512,6) -> VGPR cap 85; L0 needs
// acc[2][4]=32 + aF/bF 24 + addr ~ 75 -> fits, no spill.
// Grid (8, 4*MAXT): x = group = s*2+(e>>2) -> flat%8 pins group to one XCD.
// L0: BM=64 x N=256 x K=1024(pad), BK=32, A+B staged via global_load_lds,
// double-buffered depth-1, drain barrier per phase (R6-proven; counted ==
// drain here). Wave grid 2m x 4n, wave tile 32x64, 8 MFMA/phase.
// Staging swizzle (both-sides, rule 21): granule g of row r at slot
// g ^ ((r>>1)&3); fragment reads use the same XOR -> conflict-free b128.
// Phase-31 A tail (u16 1008..1023 of each row) reads the next row's head /
// the zeroed gap; it multiplies wt0's zero-padded K rows -> contributes 0.
// LDS union (40KB): {A-dbuf 8KB | B-dbuf 32KB} -> H0 32KB -> H1 24KB -> H2 20KB.
// H tensors XOR-swizzled: u16 idx ^= (row&7)<<3.
// mfma_f32_16x16x32_bf16: A[m=lane&15][k=quad*8+j]; B[k][n=lane&15];
// C/D col=lane&15, row=quad*4+reg (m89-verified).
__global__ __launch_bounds__(512, 6) void k_main(
    const u16* __restrict__ aevb, const u16* __restrict__ wt0,
    const u16* __restrict__ wt1, const u16* __restrict__ wt2,
    const u16* __restrict__ w3b, const u16* __restrict__ b0b,
    const u16* __restrict__ b1b, const u16* __restrict__ b2b,
    const u16* __restrict__ b3b, const int* __restrict__ w,
    float* __restrict__ accum) {
  __shared__ __align__(16) u16 L[20480];

  const int tid = threadIdx.x;
  const int g = blockIdx.x;
  const int s = g >> 1;
  const int e = (g & 1) * 4 + (blockIdx.y & 3);
  const int tile = blockIdx.y >> 2;
  const int cnt = w[s];
  if (tile * BM >= cnt) return;
  const int mRow = w[20 + s] + tile * BM;
  const int mCount = min(BM, cnt - tile * BM);
  const int se = s * NE + e;

  const int lane = tid & 63;
  const int wv = tid >> 6;       // 0..7
  const int lcol = lane & 15;
  const int quad = lane >> 4;

  // ---------------- layer 0: aevb[64x1008] @ wt0t[se][256][1024] ----------------
  {
    const u16* wt0se = wt0 + (size_t)se * 256 * 1024;
    const int wm = wv >> 2, wn = wv & 3;   // 2m x 4n, wave tile 32x64

    // A staging (tid<256): slot=tid, row=tid>>2 (0..63), pos=tid&3,
    // src granule = pos ^ ((row>>1)&3). 4KB/phase.
    // B staging (all 512, 2 calls): slots tid (rows 0..127) and 512+tid
    // (rows 128..255). 16KB/phase.
    const int rowA = tid >> 2;
    const int gAx = (tid & 3) ^ ((rowA >> 1) & 3);
    const u16* gA = aevb + (size_t)(mRow + (rowA & 63)) * 1008 + gAx * 8;
    const int rB1 = 128 + (tid >> 2);
    const int gB0x = (tid & 3) ^ (((tid >> 2) >> 1) & 3);
    const int gB1x = (tid & 3) ^ ((rB1 >> 1) & 3);
    const u16* gB0 = wt0se + (size_t)(tid >> 2) * 1024 + gB0x * 8;
    const u16* gB1 = wt0se + (size_t)rB1 * 1024 + gB1x * 8;
    const int aSt = wv * 512;            // wv<4 only (A buf = 2048 u16)
    const int bSt0 = 4096 + wv * 512;    // B rows 0..127
    const int bSt1 = 4096 + 4096 + wv * 512;  // B rows 128..255

    // fragment read swizzle (lane-constant XOR term)
    const int gsw = (quad ^ ((lcol >> 1) & 3)) * 8;
    const int aRow0 = (wm * 32 + lcol) * 32 + gsw;
    const int bRow0 = (wn * 64 + lcol) * 32 + gsw;

    f32x4 acc[2][4];
#pragma unroll
    for (int i = 0; i < 2; ++i)
#pragma unroll
      for (int j = 0; j < 4; ++j) acc[i][j] = (f32x4){0.f, 0.f, 0.f, 0.f};

    // prologue: stage phase 0 into buffer 0
    if (tid < 256) gll16(gA, &L[aSt]);
    gll16(gB0, &L[bSt0]);
    gll16(gB1, &L[bSt1]);
    __syncthreads();

#pragma unroll 2
    for (int p = 0; p < 32; ++p) {
      const int d = p & 1;
      if (p < 31) {
        const int dn = d ^ 1;
        if (tid < 256) gll16(gA + (p + 1) * 32, &L[dn * 2048 + aSt]);
        gll16(gB0 + (p + 1) * 32, &L[dn * 8192 + bSt0]);
        gll16(gB1 + (p + 1) * 32, &L[dn * 8192 + bSt1]);
      }
      const u16* Ad = &L[d * 2048];
      const u16* Bd = &L[4096 + d * 8192];
      s16x8 aF[2], bF[4];
#pragma unroll
      for (int mt = 0; mt < 2; ++mt)
        aF[mt] = __builtin_bit_cast(s16x8, *(const u16x8*)(Ad + aRow0 + mt * 512));
#pragma unroll
      for (int nt = 0; nt < 4; ++nt)
        bF[nt] = __builtin_bit_cast(s16x8, *(const u16x8*)(Bd + bRow0 + nt * 512));
      __builtin_amdgcn_s_setprio(1);
#pragma unroll
      for (int nt = 0; nt < 4; ++nt)
#pragma unroll
        for (int mt = 0; mt < 2; ++mt)
          acc[mt][nt] = __builtin_amdgcn_mfma_f32_16x16x32_bf16(aF[mt], bF[nt], acc[mt][nt], 0, 0, 0);
      __builtin_amdgcn_s_setprio(0);
      __syncthreads();
    }

    // epilogue -> H0 [64][256] swizzled (staging dead after final barrier)
#pragma unroll
    for (int nt = 0; nt < 4; ++nt) {
      const int col = wn * 64 + nt * 16 + lcol;
      const float bb = bf2f(b0b[se * 256 + col]);
#pragma unroll
      for (int mt = 0; mt < 2; ++mt) {
#pragma unroll
        for (int r = 0; r < 4; ++r) {
          const int rr = wm * 32 + mt * 16 + quad * 4 + r;
          L[(rr * 256 + col) ^ ((rr & 7) << 3)] = f2bf(celu_f(acc[mt][nt][r] + bb));
        }
      }
    }
  }
  __syncthreads();

  // ---------------- layer 1: H0[64x256] @ wt1t[192][256] ----------------
  {
    const int wm = wv >> 2, wn = wv & 3;   // 2m x 4n, wave tile 32x48
    const u16* w1se = wt1 + (size_t)se * 192 * 256;
    const u16* bp[3];
#pragma unroll
    for (int nt = 0; nt < 3; ++nt)
      bp[nt] = w1se + (size_t)(wn * 48 + nt * 16 + lcol) * 256 + quad * 8;
    f32x4 acc[2][3];
#pragma unroll
    for (int i = 0; i < 2; ++i)
#pragma unroll
      for (int j = 0; j < 3; ++j) acc[i][j] = (f32x4){0.f, 0.f, 0.f, 0.f};
    int aBase[2], aSwz[2];
#pragma unroll
    for (int mt = 0; mt < 2; ++mt) {
      const int row = wm * 32 + mt * 16 + lcol;
      aBase[mt] = row * 256 + quad * 8;
      aSwz[mt] = (row & 7) << 3;
    }
    u16x8 cB[3], nB[3];
#pragma unroll
    for (int nt = 0; nt < 3; ++nt) cB[nt] = *(const u16x8*)bp[nt];
    for (int kc = 0; kc < 8; ++kc) {
      if (kc < 7) {
#pragma unroll
        for (int nt = 0; nt < 3; ++nt) nB[nt] = *(const u16x8*)(bp[nt] + (kc + 1) * 32);
      }
      s16x8 aF[2];
#pragma unroll
      for (int mt = 0; mt < 2; ++mt)
        aF[mt] = __builtin_bit_cast(s16x8, *(const u16x8*)&L[(aBase[mt] + kc * 32) ^ aSwz[mt]]);
#pragma unroll
      for (int nt = 0; nt < 3; ++nt) {
        const s16x8 bF = __builtin_bit_cast(s16x8, cB[nt]);
#pragma unroll
        for (int mt = 0; mt < 2; ++mt)
          acc[mt][nt] = __builtin_amdgcn_mfma_f32_16x16x32_bf16(aF[mt], bF, acc[mt][nt], 0, 0, 0);
      }
      if (kc < 7) {
#pragma unroll
        for (int nt = 0; nt < 3; ++nt) cB[nt] = nB[nt];
      }
    }
    __syncthreads();  // all H0 reads done
#pragma unroll
    for (int nt = 0; nt < 3; ++nt) {
      const int col = wn * 48 + nt * 16 + lcol;
      const float bb = bf2f(b1b[se * 192 + col]);
#pragma unroll
      for (int mt = 0; mt < 2; ++mt) {
#pragma unroll
        for (int r = 0; r < 4; ++r) {
          const int rr = wm * 32 + mt * 16 + quad * 4 + r;
          L[(rr * 192 + col) ^ ((rr & 7) << 3)] = f2bf(celu_f(acc[mt][nt][r] + bb));
        }
      }
    }
  }
  __syncthreads();

  // ---------------- layer 2: H1[64x192] @ wt2t[160][192] ----------------
  {
    const int wm = wv >> 2, wn = wv & 3;   // 2m x 4n; n-tiles 10 split 2/2/3/3
    const int nN2 = (wn < 2) ? 2 : 3;
    const int t2 = (wn < 2) ? 2 * wn : 3 * wn - 2;
    const u16* w2se = wt2 + (size_t)se * 160 * 192;
    const u16* bp[3];
    for (int nt = 0; nt < nN2; ++nt)
      bp[nt] = w2se + (size_t)((t2 + nt) * 16 + lcol) * 192 + quad * 8;
    f32x4 acc[2][3];
#pragma unroll
    for (int i = 0; i < 2; ++i)
#pragma unroll
      for (int j = 0; j < 3; ++j) acc[i][j] = (f32x4){0.f, 0.f, 0.f, 0.f};
    int aBase[2], aSwz[2];
#pragma unroll
    for (int mt = 0; mt < 2; ++mt) {
      const int row = wm * 32 + mt * 16 + lcol;
      aBase[mt] = row * 192 + quad * 8;
      aSwz[mt] = (row & 7) << 3;
    }
    u16x8 cB[3], nB[3];
    for (int nt = 0; nt < nN2; ++nt) cB[nt] = *(const u16x8*)bp[nt];
    for (int kc = 0; kc < 6; ++kc) {
      if (kc < 5) {
        for (int nt = 0; nt < nN2; ++nt) nB[nt] = *(const u16x8*)(bp[nt] + (kc + 1) * 32);
      }
      s16x8 aF[2];
#pragma unroll
      for (int mt = 0; mt < 2; ++mt)
        aF[mt] = __builtin_bit_cast(s16x8, *(const u16x8*)&L[(aBase[mt] + kc * 32) ^ aSwz[mt]]);
      for (int nt = 0; nt < nN2; ++nt) {
        const s16x8 bF = __builtin_bit_cast(s16x8, cB[nt]);
#pragma unroll
        for (int mt = 0; mt < 2; ++mt)
          acc[mt][nt] = __builtin_amdgcn_mfma_f32_16x16x32_bf16(aF[mt], bF, acc[mt][nt], 0, 0, 0);
      }
      if (kc < 5) {
        for (int nt = 0; nt < nN2; ++nt) cB[nt] = nB[nt];
      }
    }
    __syncthreads();  // all H1 reads done
    for (int nt = 0; nt < nN2; ++nt) {
      const int col = (t2 + nt) * 16 + lcol;
      const float bb = bf2f(b2b[se * 160 + col]);
#pragma unroll
      for (int mt = 0; mt < 2; ++mt) {
#pragma unroll
        for (int r = 0; r < 4; ++r) {
          const int rr = wm * 32 + mt * 16 + quad * 4 + r;
          L[(rr * 160 + col) ^ ((rr & 7) << 3)] = f2bf(celu_f(acc[mt][nt][r] + bb));
        }
      }
    }
  }
  __syncthreads();

  // ---------------- layer 3: dot(H2[64x160], W3) + b3, reduce ----------------
  {
    const int row = tid >> 3;   // 0..63
    const int pp = tid & 7;     // 8 parts per row
    const u16* w3p = w3b + se * 160;
    float dotv = 0.f;
    // granules pp, pp+8 (all), 16+pp (pp<4): 20 granules of 8 cols
#pragma unroll
    for (int j = 0; j < 2; ++j) {
      const int ci = (pp + 8 * j) * 8;
      const u16x8 hv = *(const u16x8*)&L[(row * 160 + ci) ^ ((row & 7) << 3)];
      const u16x8 wv8 = *(const u16x8*)(w3p + ci);
#pragma unroll
      for (int t2 = 0; t2 < 8; ++t2)
        dotv = fmaf(bf2f(hv[t2]), bf2f(wv8[t2]), dotv);
    }
    if (pp < 4) {
      const int ci = (16 + pp) * 8;
      const u16x8 hv = *(const u16x8*)&L[(row * 160 + ci) ^ ((row & 7) << 3)];
      const u16x8 wv8 = *(const u16x8*)(w3p + ci);
#pragma unroll
      for (int t2 = 0; t2 < 8; ++t2)
        dotv = fmaf(bf2f(hv[t2]), bf2f(wv8[t2]), dotv);
    }
    dotv += __shfl_xor(dotv, 1);
    dotv += __shfl_xor(dotv, 2);
    dotv += __shfl_xor(dotv, 4);
    float v = (pp == 0 && row < mCount) ? (dotv + bf2f(b3b[se])) : 0.f;
    v += __shfl_xor(v, 8);
    v += __shfl_xor(v, 16);
    v += __shfl_xor(v, 32);
    float* redf = (float*)&L[10368];  // beyond H2 swizzled extent (<10296)
    if (lane == 0) redf[wv] = v;
    __syncthreads();
    if (tid == 0) {
      float tot = 0.f;
#pragma unroll
      for (int i = 0; i < 8; ++i) tot += redf[i];
      atomicAdd(accum, tot * 0.125f);
    }
  }
}

__global__ void k_final(const float* __restrict__ accum, u32* __restrict__ out) {
  u32 h = (u32)f2bf(accum[0]);
  out[0] = (h << 16) | h;
}

extern "C" void kernel_launch(void* const* d_in, const int* in_sizes, int n_in,
                              void* d_out, int out_size, void* d_ws, size_t ws_size,
                              hipStream_t stream) {
  const void* aev = d_in[0];
  const void* species = d_in[1];
  const void* W0 = d_in[2];
  const void* b0 = d_in[3];
  const void* W1 = d_in[4];
  const void* b1 = d_in[5];
  const void* W2 = d_in[6];
  const void* b2 = d_in[7];
  const void* W3 = d_in[8];
  const void* b3 = d_in[9];

  int* wsI = (int*)d_ws;
  float* accum = (float*)((char*)d_ws + 17 * 4);
  int* order = wsI + 1024;  // byte offset 4096, 80000B
  char* wsB = (char*)d_ws;

  const size_t oB0 = 131072;
  const size_t oB1 = 147456;
  const size_t oB2 = 159744;
  const size_t oB3 = 169984;
  const size_t oW3 = 170048;
  const size_t oAevb = 262144;         // 20608*2016 = 41545728 -> 41807872
  const size_t oGap = 41807872;        // 4KB zeroed guard
  const size_t oWt0 = 41811968;        // 16777216 -> 58589184
  const size_t oWt1 = 58589184;        // 3145728 -> 61734912
  const size_t oWt2 = 61734912;        // 1966080 -> 63700992

  u16* aevb = (u16*)(wsB + oAevb);
  u16* wt0 = (u16*)(wsB + oWt0);
  u16* wt1 = (u16*)(wsB + oWt1);
  u16* wt2 = (u16*)(wsB + oWt2);
  u16* w3b = (u16*)(wsB + oW3);
  u16* b0b = (u16*)(wsB + oB0);
  u16* b1b = (u16*)(wsB + oB1);
  u16* b2b = (u16*)(wsB + oB2);
  u16* b3b = (u16*)(wsB + oB3);

  hipLaunchKernelGGL(k_probe0, dim3(1), dim3(256), 0, stream, aev, species, wsI);
  hipLaunchKernelGGL(k_count, dim3((NA + 255) / 256), dim3(256), 0, stream, species, wsI);
  hipLaunchKernelGGL(k_scatsml, dim3(80), dim3(256), 0, stream, species, wsI, order,
                     b0, b1, b2, b3, W3, b0b, b1b, b2b, b3b, w3b, (u16*)(wsB + oGap));
  hipLaunchKernelGGL(k_gather, dim3(MAXROWS / 4), dim3(512), 0, stream, aev, wsI, order, aevb);
  hipLaunchKernelGGL(k_tr3, dim3(32, 16, 4), dim3(256), 0, stream, W0, W1, W2,
                     wt0, wt1, wt2, wsI);
  hipLaunchKernelGGL(k_main, dim3(8, 4 * MAXT), dim3(512), 0, stream,
                     aevb, wt0, wt1, wt2, w3b, b0b, b1b, b2b, b3b, wsI, accum);
  hipLaunchKernelGGL(k_final, dim3(1), dim3(1), 0, stream, accum, (u32*)d_out);
}

// Round 10
// 426.258 us; speedup vs baseline: 1.9116x; 1.7489x over previous
//
#include <hip/hip_runtime.h>
#include <cmath>

#define NA 20000
#define NS 4
#define NE 8
#define DD 1008
#define BM 128
#define MAXT 157      // ceil(20000/128)
#define MAXROWS 20608 // gather coverage, >= worst padded total
#define GATHB (MAXROWS / 2)   // gather blocks (2 rows x 256 thr)
#define TRB 2048              // transpose blocks (32*16*4)

typedef unsigned short u16;
typedef unsigned int u32;
typedef unsigned long long u64;
typedef u16 u16x8 __attribute__((ext_vector_type(8)));
typedef u16 u16x4 __attribute__((ext_vector_type(4)));
typedef float f32x4 __attribute__((ext_vector_type(4)));
typedef short s16x8 __attribute__((ext_vector_type(8)));

__device__ __forceinline__ float bf2f(u16 h) {
  u32 u = ((u32)h) << 16;
  return __builtin_bit_cast(float, u);
}
__device__ __forceinline__ u16 f2bf(float f) {
  u32 b = __builtin_bit_cast(u32, f);
  u32 lsb = (b >> 16) & 1;
  return (u16)((b + 0x7fffu + lsb) >> 16);
}
// celu(x), alpha=0.1: x>0 ? x : 0.1*(e^{10x}-1). exp via v_exp_f32 (2^t).
__device__ __forceinline__ float celu_f(float x) {
#if __has_builtin(__builtin_amdgcn_exp2f)
  float e = __builtin_amdgcn_exp2f(x * 14.426950408889634f);
#else
  float e = exp2f(x * 14.426950408889634f);
#endif
  return x > 0.f ? x : 0.1f * (e - 1.f);
}
__device__ __forceinline__ float gf(const void* g, size_t i, bool isF32) {
  return isF32 ? ((const float*)g)[i] : bf2f(((const u16*)g)[i]);
}

// async global->LDS, 16B per lane; lds base wave-uniform, lane l -> base+l*16.
__device__ __forceinline__ void gll16(const void* g, const u16* lds) {
#if __has_builtin(__builtin_amdgcn_global_load_lds)
  __builtin_amdgcn_global_load_lds(
      (const __attribute__((address_space(1))) u32*)g,
      (__attribute__((address_space(3))) u32*)(u16*)lds, 16, 0, 0);
#else
  int l = threadIdx.x & 63;
  *(f32x4*)((u16*)lds + l * 8) = *(const f32x4*)g;
#endif
}

// ws ints: [0..3] counts, [4..7] cursors, [13..16] atom-base prefix,
// [17] f32 accum, [18] fp32-flag, [19] i64-flag, [20..23] padded segStart,
// [24] padded total, [25] count-ticket; order at int 1024.
__global__ void k_probe0(const void* __restrict__ aev, const void* __restrict__ species,
                         int* __restrict__ w) {
  __shared__ int sh[2];
  int tid = threadIdx.x;
  if (tid < 64) w[tid] = 0;
  if (tid == 0) { sh[0] = 0; sh[1] = 0; }
  __syncthreads();
  const u16* a = (const u16*)aev;
  int bad = 0;
  for (int i = 0; i < 16; ++i) {
    u16 h = a[tid * 16 + i];
    int ex = (h >> 7) & 0xFF;
    if (ex < 107 || ex > 147) ++bad;
  }
  atomicAdd(&sh[0], bad);
  const int* sp = (const int*)species;
  int odd = 0;
  for (int i = 0; i < 4; ++i)
    if (sp[(tid * 4 + i) * 2 + 1] != 0) ++odd;
  atomicAdd(&sh[1], odd);
  __syncthreads();
  if (tid == 0) {
    w[18] = (sh[0] > 400) ? 1 : 0;
    w[19] = (sh[1] == 0) ? 1 : 0;
  }
}

__device__ __forceinline__ int get_species(const void* sp, int i, bool i64) {
  int s = i64 ? ((const int*)sp)[2 * i] : ((const int*)sp)[i];
  return s < 0 ? 0 : (s > 3 ? 3 : s);
}

// count + fused scan (last-block ticket; non-blocking, no spin)
__global__ void k_count(const void* __restrict__ species, int* __restrict__ w) {
  int i = blockIdx.x * 256 + threadIdx.x;
  int lane = threadIdx.x & 63;
  int s = (i < NA) ? get_species(species, i, w[19] != 0) : -1;
  for (int sp = 0; sp < 4; ++sp) {
    u64 m = __ballot(s == sp);
    if (m != 0 && lane == (__ffsll((long long)m) - 1))
      atomicAdd(&w[sp], __popcll(m));
  }
  __syncthreads();
  if (threadIdx.x == 0) {
    __threadfence();
    if (atomicAdd(&w[25], 1) == (int)gridDim.x - 1) {
      int b = 0, pb = 0;
      for (int sp = 0; sp < 4; ++sp) {
        int c = atomicAdd(&w[sp], 0);  // coherent read
        w[13 + sp] = b; b += c;
        w[20 + sp] = pb; pb += ((c + 127) >> 7) << 7;  // 128-row padding
      }
      w[24] = pb;
    }
  }
}

// scatter only (79 blocks)
__global__ void k_scat(const void* __restrict__ species, int* __restrict__ w,
                       int* __restrict__ order) {
  int i = blockIdx.x * 256 + threadIdx.x;
  int lane = threadIdx.x & 63;
  int s = (i < NA) ? get_species(species, i, w[19] != 0) : -1;
  for (int sp = 0; sp < 4; ++sp) {
    u64 m = __ballot(s == sp);
    if (m == 0) continue;
    int leader = __ffsll((long long)m) - 1;
    int base = 0;
    if (lane == leader) base = atomicAdd(&w[4 + sp], __popcll(m));
    base = __shfl(base, leader);
    if (s == sp) {
      int rank = __popcll(m & ((lane == 63) ? 0x7fffffffffffffffULL : ((1ULL << lane) - 1)));
      order[w[13 + sp] + base + rank] = i;
    }
  }
}

// one 64x64 transpose tile: W [se][K][N] -> bf16 [se][N][Kpad], zero-padded K
__device__ void tr_tile(const void* __restrict__ W, u16* __restrict__ out,
                        int K, int N, int Kpad, bool isF32, int se,
                        int k0, int n0, int t, u16 (*tile)[68]) {
  const size_t inBase = (size_t)se * K * N;
#pragma unroll
  for (int c = 0; c < 4; ++c) {
    int kk = (t >> 4) + c * 16, nn = (t & 15) * 4;
    int k = k0 + kk, n = n0 + nn;
    u16x4 v = {0, 0, 0, 0};
    if (k < K && n < N) {
      if (isF32) {
        f32x4 f = *(const f32x4*)((const float*)W + inBase + (size_t)k * N + n);
        v[0] = f2bf(f[0]); v[1] = f2bf(f[1]); v[2] = f2bf(f[2]); v[3] = f2bf(f[3]);
      } else {
        v = *(const u16x4*)((const u16*)W + inBase + (size_t)k * N + n);
      }
    }
    *(u16x4*)(&tile[kk][nn]) = v;
  }
  __syncthreads();
  int nloc = t >> 2, ks = (t & 3) * 16;
  if (n0 + nloc < N) {
    u16x8 o0, o1;
#pragma unroll
    for (int i = 0; i < 8; ++i) { o0[i] = tile[ks + i][nloc]; o1[i] = tile[ks + 8 + i][nloc]; }
    size_t ob = (size_t)se * N * Kpad + (size_t)(n0 + nloc) * Kpad + k0 + ks;
    *(u16x8*)(out + ob) = o0;
    *(u16x8*)(out + ob + 8) = o1;
  }
}

// fused: gather (blocks 0..GATHB-1) + 3 weight transposes (next TRB blocks)
// + small tensors (last block). 256 threads. All parts independent.
__global__ void k_gts(const void* __restrict__ aev, const int* __restrict__ w,
                      const int* __restrict__ order, u16* __restrict__ aevb,
                      const void* __restrict__ W0, const void* __restrict__ W1,
                      const void* __restrict__ W2, u16* __restrict__ o0,
                      u16* __restrict__ o1, u16* __restrict__ o2,
                      const void* b0, const void* b1, const void* b2, const void* b3,
                      const void* W3, u16* ob0, u16* ob1, u16* ob2, u16* ob3,
                      u16* oW3, u16* gap) {
  __shared__ u16 tile[64][68];
  const bool isF32 = (w[18] != 0);
  const int bid = blockIdx.x;
  const int t = threadIdx.x;
  if (bid < GATHB) {
    // gather aev into sorted, per-species 128-padded bf16 rows; pads zeroed.
    const int r = bid * 2 + (t >> 7);
    const int j = t & 127;
    if (j >= 126) return;
    const int s = (r >= w[21]) + (r >= w[22]) + (r >= w[23]);
    const int local = r - w[20 + s];
    u16x8 v = {0, 0, 0, 0, 0, 0, 0, 0};
    if (local < w[s]) {
      const int src = order[w[13 + s] + local];
      if (isF32) {
        const float* p = (const float*)aev + (size_t)src * DD + j * 8;
        const f32x4 f0 = *(const f32x4*)p;
        const f32x4 f1 = *(const f32x4*)(p + 4);
#pragma unroll
        for (int i = 0; i < 4; ++i) { v[i] = f2bf(f0[i]); v[4 + i] = f2bf(f1[i]); }
      } else {
        v = *(const u16x8*)((const u16*)aev + (size_t)src * DD + j * 8);
      }
    }
    *(u16x8*)(aevb + (size_t)r * DD + j * 8) = v;
    return;
  }
  if (bid < GATHB + TRB) {
    const int b2i = bid - GATHB;
    const int se = b2i & 31;
    const int rem = b2i >> 5;
    const int by = rem & 15, bz = rem >> 4;
    tr_tile(W0, o0, 1008, 256, 1024, isF32, se, by * 64, bz * 64, t, tile);
    if (by < 4 && bz < 3) {
      __syncthreads();
      tr_tile(W1, o1, 256, 192, 256, isF32, se, by * 64, bz * 64, t, tile);
    }
    if (by < 3 && bz < 3) {
      __syncthreads();
      tr_tile(W2, o2, 192, 160, 192, isF32, se, by * 64, bz * 64, t, tile);
    }
    return;
  }
  // smalls + gap-zero
  for (int i = t; i < 32 * 256; i += 256) ob0[i] = f2bf(gf(b0, i, isF32));
  for (int i = t; i < 32 * 192; i += 256) ob1[i] = f2bf(gf(b1, i, isF32));
  for (int i = t; i < 32 * 160; i += 256) ob2[i] = f2bf(gf(b2, i, isF32));
  for (int i = t; i < 32 * 160; i += 256) oW3[i] = f2bf(gf(W3, i, isF32));
  if (t < 32) ob3[t] = f2bf(gf(b3, t, isF32));
  u16x8 z = {0, 0, 0, 0, 0, 0, 0, 0};
  *(u16x8*)(gap + t * 8) = z;  // zero 4KB tail after aevb
}

// ================= fused MFMA kernel (R2-proven: 184-190 us) =================
// 512 threads = 8 waves; block = 128 atoms (one species) x one e.
// Grid (8, 4*MAXT): x = group = s*2+(e>>2) -> flat%8 pins group to one XCD.
// L0: BM=128 x N=256 x K=1024(pad), BK=32, double-buffered LDS staging via
// global_load_lds, one __syncthreads per phase (drain beat counted-vmcnt
// in R6's A/B: 184-190 vs 193-195).
// Bank-conflict-free staging (rule #21: swizzle source AND read, dest linear):
// 16B granule g of row r stored at slot g ^ ((r>>1)&3); fragment reads hit
// all 8 bank-groups across any 8 consecutive lanes.
// LDS union (64KB): {A-dbuf 16KB | B-dbuf 32KB} -> H0 64KB -> H1 48KB -> H2 40KB.
// H tensors XOR-swizzled: u16 idx ^= (row&7)<<3 (2-way max on all read paths).
// mfma_f32_16x16x32_bf16: A[m=lane&15][k=quad*8+j]; B[k][n=lane&15];
// C/D col=lane&15, row=quad*4+reg (m89-verified).
__global__ __launch_bounds__(512, 4) void k_main(
    const u16* __restrict__ aevb, const u16* __restrict__ wt0,
    const u16* __restrict__ wt1, const u16* __restrict__ wt2,
    const u16* __restrict__ w3b, const u16* __restrict__ b0b,
    const u16* __restrict__ b1b, const u16* __restrict__ b2b,
    const u16* __restrict__ b3b, const int* __restrict__ w,
    float* __restrict__ accum) {
  __shared__ __align__(16) u16 L[32768];

  const int tid = threadIdx.x;
  const int g = blockIdx.x;
  const int s = g >> 1;
  const int e = (g & 1) * 4 + (blockIdx.y & 3);
  const int tile = blockIdx.y >> 2;
  const int cnt = w[s];
  if (tile * BM >= cnt) return;
  const int mRow = w[20 + s] + tile * BM;
  const int mCount = min(BM, cnt - tile * BM);
  const int se = s * NE + e;

  const int lane = tid & 63;
  const int wv = tid >> 6;
  const int lcol = lane & 15;
  const int quad = lane >> 4;

  // ---------------- layer 0: aevb[128x1008] @ wt0t[se][256][1024] ----------------
  {
    const u16* wt0se = wt0 + (size_t)se * 256 * 1024;
    // staging: thread t owns 16B slot t (A), slots t and t+512 (B).
    // slot s -> row = s>>2, stores global granule g = (s&3) ^ ((row>>1)&3).
    const int rowA = tid >> 2;
    const int gAx = (tid & 3) ^ ((rowA >> 1) & 3);
    const char* gA = (const char*)aevb + (size_t)(mRow + rowA) * 2016 + gAx * 16;
    const int rB1 = 128 + (tid >> 2);
    const int gB0x = (tid & 3) ^ (((tid >> 2) >> 1) & 3);
    const int gB1x = (tid & 3) ^ ((rB1 >> 1) & 3);
    const char* gB0 = (const char*)wt0se + (size_t)(tid >> 2) * 2048 + gB0x * 16;
    const char* gB1 = (const char*)wt0se + (size_t)rB1 * 2048 + gB1x * 16;
    const int aSt = wv * 512;            // u16 idx within A buf (wave-uniform)
    const int bSt = 8192 + wv * 512;     // B rows 0..127
    const int bSt2 = 8192 + 4096 + wv * 512;  // B rows 128..255

    const int wm = wv >> 2, wn = wv & 3;
    // fragment read swizzle: granule = quad ^ ((row>>1)&3); row = ..+lcol so
    // the XOR term is lane-constant: (lcol>>1)&3.
    const int gsw = (quad ^ ((lcol >> 1) & 3)) * 8;
    const int aRow0 = (wm * 64 + lcol) * 32 + gsw;
    const int bRow0 = 8192 + (wn * 64 + lcol) * 32 + gsw;

    f32x4 acc[4][4];
#pragma unroll
    for (int i = 0; i < 4; ++i)
#pragma unroll
      for (int j = 0; j < 4; ++j) acc[i][j] = (f32x4){0.f, 0.f, 0.f, 0.f};

    // prologue: stage phase 0 into buffer 0
    gll16(gA, &L[aSt]); gA += 64;
    gll16(gB0, &L[bSt]); gB0 += 64;
    gll16(gB1, &L[bSt2]); gB1 += 64;
    __syncthreads();

    for (int p = 0; p < 32; ++p) {
      const int d = p & 1;
      if (p < 31) {
        const int dn = d ^ 1;
        gll16(gA, &L[dn * 4096 + aSt]); gA += 64;
        gll16(gB0, &L[dn * 8192 + bSt]); gB0 += 64;
        gll16(gB1, &L[dn * 8192 + bSt2]); gB1 += 64;
      }
      const u16* Ad = &L[d * 4096];
      const u16* Bd = &L[d * 8192];
      s16x8 aF[4], bF[4];
#pragma unroll
      for (int mt = 0; mt < 4; ++mt)
        aF[mt] = __builtin_bit_cast(s16x8, *(const u16x8*)(Ad + aRow0 + mt * 512));
#pragma unroll
      for (int nt = 0; nt < 4; ++nt)
        bF[nt] = __builtin_bit_cast(s16x8, *(const u16x8*)(Bd + bRow0 + nt * 512));
      __builtin_amdgcn_s_setprio(1);
#pragma unroll
      for (int nt = 0; nt < 4; ++nt)
#pragma unroll
        for (int mt = 0; mt < 4; ++mt)
          acc[mt][nt] = __builtin_amdgcn_mfma_f32_16x16x32_bf16(aF[mt], bF[nt], acc[mt][nt], 0, 0, 0);
      __builtin_amdgcn_s_setprio(0);
      __syncthreads();
    }

    // epilogue -> H0 [128][256] swizzled (staging region dead)
#pragma unroll
    for (int nt = 0; nt < 4; ++nt) {
      const int col = wn * 64 + nt * 16 + lcol;
      const float bb = bf2f(b0b[se * 256 + col]);
#pragma unroll
      for (int mt = 0; mt < 4; ++mt) {
#pragma unroll
        for (int r = 0; r < 4; ++r) {
          const int rr = wm * 64 + mt * 16 + quad * 4 + r;
          L[(rr * 256 + col) ^ ((rr & 7) << 3)] = f2bf(celu_f(acc[mt][nt][r] + bb));
        }
      }
    }
  }
  __syncthreads();

  // ---------------- layer 1: H0[128x256] @ wt1t[192][256] ----------------
  {
    const int wm = wv >> 2, wn = wv & 3;
    const u16* w1se = wt1 + (size_t)se * 192 * 256;
    const u16* bp[3];
#pragma unroll
    for (int nt = 0; nt < 3; ++nt)
      bp[nt] = w1se + (size_t)(wn * 48 + nt * 16 + lcol) * 256 + quad * 8;
    f32x4 acc[4][3];
#pragma unroll
    for (int i = 0; i < 4; ++i)
#pragma unroll
      for (int j = 0; j < 3; ++j) acc[i][j] = (f32x4){0.f, 0.f, 0.f, 0.f};
    int aBase[4], aSwz[4];
#pragma unroll
    for (int mt = 0; mt < 4; ++mt) {
      const int row = wm * 64 + mt * 16 + lcol;
      aBase[mt] = row * 256 + quad * 8;
      aSwz[mt] = (row & 7) << 3;
    }
    u16x8 cB[3], nB[3];
#pragma unroll
    for (int nt = 0; nt < 3; ++nt) cB[nt] = *(const u16x8*)bp[nt];
    for (int kc = 0; kc < 8; ++kc) {
      if (kc < 7) {
#pragma unroll
        for (int nt = 0; nt < 3; ++nt) nB[nt] = *(const u16x8*)(bp[nt] + (kc + 1) * 32);
      }
      s16x8 aF[4];
#pragma unroll
      for (int mt = 0; mt < 4; ++mt)
        aF[mt] = __builtin_bit_cast(s16x8, *(const u16x8*)&L[(aBase[mt] + kc * 32) ^ aSwz[mt]]);
#pragma unroll
      for (int nt = 0; nt < 3; ++nt) {
        const s16x8 bF = __builtin_bit_cast(s16x8, cB[nt]);
#pragma unroll
        for (int mt = 0; mt < 4; ++mt)
          acc[mt][nt] = __builtin_amdgcn_mfma_f32_16x16x32_bf16(aF[mt], bF, acc[mt][nt], 0, 0, 0);
      }
      if (kc < 7) {
#pragma unroll
        for (int nt = 0; nt < 3; ++nt) cB[nt] = nB[nt];
      }
    }
    __syncthreads();  // all H0 reads done
#pragma unroll
    for (int nt = 0; nt < 3; ++nt) {
      const int col = wn * 48 + nt * 16 + lcol;
      const float bb = bf2f(b1b[se * 192 + col]);
#pragma unroll
      for (int mt = 0; mt < 4; ++mt) {
#pragma unroll
        for (int r = 0; r < 4; ++r) {
          const int rr = wm * 64 + mt * 16 + quad * 4 + r;
          L[(rr * 192 + col) ^ ((rr & 7) << 3)] = f2bf(celu_f(acc[mt][nt][r] + bb));
        }
      }
    }
  }
  __syncthreads();

  // ---------------- layer 2: H1[128x192] @ wt2t[160][192] ----------------
  {
    const int wm = wv >> 1, wn = wv & 1;
    const u16* w2se = wt2 + (size_t)se * 160 * 192;
    const u16* bp[5];
#pragma unroll
    for (int nt = 0; nt < 5; ++nt)
      bp[nt] = w2se + (size_t)(wn * 80 + nt * 16 + lcol) * 192 + quad * 8;
    f32x4 acc[2][5];
#pragma unroll
    for (int i = 0; i < 2; ++i)
#pragma unroll
      for (int j = 0; j < 5; ++j) acc[i][j] = (f32x4){0.f, 0.f, 0.f, 0.f};
    int aBase[2], aSwz[2];
#pragma unroll
    for (int mt = 0; mt < 2; ++mt) {
      const int row = wm * 32 + mt * 16 + lcol;
      aBase[mt] = row * 192 + quad * 8;
      aSwz[mt] = (row & 7) << 3;
    }
    u16x8 cB[5], nB[5];
#pragma unroll
    for (int nt = 0; nt < 5; ++nt) cB[nt] = *(const u16x8*)bp[nt];
    for (int kc = 0; kc < 6; ++kc) {
      if (kc < 5) {
#pragma unroll
        for (int nt = 0; nt < 5; ++nt) nB[nt] = *(const u16x8*)(bp[nt] + (kc + 1) * 32);
      }
      s16x8 aF[2];
#pragma unroll
      for (int mt = 0; mt < 2; ++mt)
        aF[mt] = __builtin_bit_cast(s16x8, *(const u16x8*)&L[(aBase[mt] + kc * 32) ^ aSwz[mt]]);
#pragma unroll
      for (int nt = 0; nt < 5; ++nt) {
        const s16x8 bF = __builtin_bit_cast(s16x8, cB[nt]);
#pragma unroll
        for (int mt = 0; mt < 2; ++mt)
          acc[mt][nt] = __builtin_amdgcn_mfma_f32_16x16x32_bf16(aF[mt], bF, acc[mt][nt], 0, 0, 0);
      }
      if (kc < 5) {
#pragma unroll
        for (int nt = 0; nt < 5; ++nt) cB[nt] = nB[nt];
      }
    }
    __syncthreads();  // all H1 reads done
#pragma unroll
    for (int nt = 0; nt < 5; ++nt) {
      const int col = wn * 80 + nt * 16 + lcol;
      const float bb = bf2f(b2b[se * 160 + col]);
#pragma unroll
      for (int mt = 0; mt < 2; ++mt) {
#pragma unroll
        for (int r = 0; r < 4; ++r) {
          const int rr = wm * 32 + mt * 16 + quad * 4 + r;
          L[(rr * 160 + col) ^ ((rr & 7) << 3)] = f2bf(celu_f(acc[mt][nt][r] + bb));
        }
      }
    }
  }
  __syncthreads();

  // ---------------- layer 3: dot(H2[128x160], W3) + b3, reduce ----------------
  {
    const int row = tid >> 2;   // 0..127
    const int pp = tid & 3;
    const u16* w3p = w3b + se * 160;
    float dotv = 0.f;
#pragma unroll
    for (int j = 0; j < 5; ++j) {
      const int ci = (pp + 4 * j) * 8;
      const u16x8 hv = *(const u16x8*)&L[(row * 160 + ci) ^ ((row & 7) << 3)];
      const u16x8 wv8 = *(const u16x8*)(w3p + ci);
#pragma unroll
      for (int t2 = 0; t2 < 8; ++t2)
        dotv = fmaf(bf2f(hv[t2]), bf2f(wv8[t2]), dotv);
    }
    dotv += __shfl_xor(dotv, 1);
    dotv += __shfl_xor(dotv, 2);
    float v = (pp == 0 && row < mCount) ? (dotv + bf2f(b3b[se])) : 0.f;
    v += __shfl_xor(v, 4);
    v += __shfl_xor(v, 8);
    v += __shfl_xor(v, 16);
    v += __shfl_xor(v, 32);
    float* redf = (float*)&L[20608];  // beyond H2 swizzled extent
    if (lane == 0) redf[wv] = v;
    __syncthreads();
    if (tid == 0) {
      float tot = 0.f;
#pragma unroll
      for (int i = 0; i < 8; ++i) tot += redf[i];
      atomicAdd(accum, tot * 0.125f);
    }
  }
}

__global__ void k_final(const float* __restrict__ accum, u32* __restrict__ out) {
  u32 h = (u32)f2bf(accum[0]);
  out[0] = (h << 16) | h;
}

extern "C" void kernel_launch(void* const* d_in, const int* in_sizes, int n_in,
                              void* d_out, int out_size, void* d_ws, size_t ws_size,
                              hipStream_t stream) {
  const void* aev = d_in[0];
  const void* species = d_in[1];
  const void* W0 = d_in[2];
  const void* b0 = d_in[3];
  const void* W1 = d_in[4];
  const void* b1 = d_in[5];
  const void* W2 = d_in[6];
  const void* b2 = d_in[7];
  const void* W3 = d_in[8];
  const void* b3 = d_in[9];

  int* wsI = (int*)d_ws;
  float* accum = (float*)((char*)d_ws + 17 * 4);
  int* order = wsI + 1024;  // byte offset 4096, 80000B
  char* wsB = (char*)d_ws;

  const size_t oB0 = 131072;
  const size_t oB1 = 147456;
  const size_t oB2 = 159744;
  const size_t oB3 = 169984;
  const size_t oW3 = 170048;
  const size_t oAevb = 262144;         // 20608*2016 = 41545728 -> 41807872
  const size_t oGap = 41807872;        // 4KB zeroed guard
  const size_t oWt0 = 41811968;        // 16777216 -> 58589184
  const size_t oWt1 = 58589184;        // 3145728 -> 61734912
  const size_t oWt2 = 61734912;        // 1966080 -> 63700992

  u16* aevb = (u16*)(wsB + oAevb);
  u16* wt0 = (u16*)(wsB + oWt0);
  u16* wt1 = (u16*)(wsB + oWt1);
  u16* wt2 = (u16*)(wsB + oWt2);
  u16* w3b = (u16*)(wsB + oW3);
  u16* b0b = (u16*)(wsB + oB0);
  u16* b1b = (u16*)(wsB + oB1);
  u16* b2b = (u16*)(wsB + oB2);
  u16* b3b = (u16*)(wsB + oB3);

  hipLaunchKernelGGL(k_probe0, dim3(1), dim3(256), 0, stream, aev, species, wsI);
  hipLaunchKernelGGL(k_count, dim3((NA + 255) / 256), dim3(256), 0, stream, species, wsI);
  hipLaunchKernelGGL(k_scat, dim3((NA + 255) / 256), dim3(256), 0, stream, species, wsI, order);
  hipLaunchKernelGGL(k_gts, dim3(GATHB + TRB + 1), dim3(256), 0, stream,
                     aev, wsI, order, aevb, W0, W1, W2, wt0, wt1, wt2,
                     b0, b1, b2, b3, W3, b0b, b1b, b2b, b3b, w3b, (u16*)(wsB + oGap));
  hipLaunchKernelGGL(k_main, dim3(8, 4 * MAXT), dim3(512), 0, stream,
                     aevb, wt0, wt1, wt2, w3b, b0b, b1b, b2b, b3b, wsI, accum);
  hipLaunchKernelGGL(k_final, dim3(1), dim3(1), 0, stream, accum, (u32*)d_out);
}